// Round 7
// baseline (267.852 us; speedup 1.0000x reference)
//
#include <hip/hip_runtime.h>
#include <hip/hip_bf16.h>
#include <math.h>

typedef __bf16 bf16;
typedef __bf16 bf16x8 __attribute__((ext_vector_type(8)));
typedef float f32x4 __attribute__((ext_vector_type(4)));

#define MFMA16(a, b, c) __builtin_amdgcn_mfma_f32_16x16x32_bf16((a), (b), (c), 0, 0, 0)

// async global->LDS, 16B per lane. LDS dest = wave-uniform base + lane*16.
__device__ __forceinline__ void gl_lds16(const void* g, void* l) {
    __builtin_amdgcn_global_load_lds(
        (__attribute__((address_space(1))) void*)(g),
        (__attribute__((address_space(3))) void*)(l),
        16, 0, 0);
}

// ---------------------------------------------------------------------------
// fp32 -> bf16 conversion: 4 weights (1M) + optionally 3 token tensors (4M).
// ---------------------------------------------------------------------------
__global__ __launch_bounds__(256) void cvt7(
    const float* __restrict__ w0, const float* __restrict__ w1,
    const float* __restrict__ w2, const float* __restrict__ w3,
    const float* __restrict__ x0, const float* __restrict__ x1,
    const float* __restrict__ x2, bf16* __restrict__ dst) {
    const int z = blockIdx.y;
    const float* src;
    bf16* out;
    if (z < 4) {
        if (blockIdx.x >= 512) return;
        src = (z == 0) ? w0 : (z == 1) ? w1 : (z == 2) ? w2 : w3;
        out = dst + (size_t)z * 1048576;
    } else {
        src = (z == 4) ? x0 : (z == 5) ? x1 : x2;
        out = dst + 4 * 1048576 + (size_t)(z - 4) * 4194304;
    }
    const int i = (blockIdx.x * 256 + threadIdx.x) * 8;
    float4 a = ((const float4*)(src + i))[0];
    float4 b = ((const float4*)(src + i))[1];
    bf16x8 o;
    o[0] = (bf16)a.x; o[1] = (bf16)a.y; o[2] = (bf16)a.z; o[3] = (bf16)a.w;
    o[4] = (bf16)b.x; o[5] = (bf16)b.y; o[6] = (bf16)b.z; o[7] = (bf16)b.w;
    *(bf16x8*)(out + i) = o;
}

// ---------------------------------------------------------------------------
// Pure-bf16 m97-style GEMM, tile 128 x (NI*32). NI=4 -> 128x128, NI=8 -> 128x256.
// EP 0: scatter bf16 -> [B,H,S,dk]   EP 1: fp32 [M,1024]   EP 2: V^T [B,H,dk,S]
// ---------------------------------------------------------------------------
template <int EP, int NI>
__device__ __forceinline__ void gemm_bf(const bf16* __restrict__ A,
                                        const bf16* __restrict__ B,
                                        void* __restrict__ Cv,
                                        const int m0, const int n0) {
    constexpr int K = 1024;
    __shared__ __align__(16) bf16 As[128 * 32];
    __shared__ __align__(16) bf16 Bs[NI * 32 * 32];

    const int t = threadIdx.x;
    const int lane = t & 63;
    const int w = t >> 6;
    const int wm = (w & 1) * 64;
    const int wn = (w >> 1) * (NI * 16);
    const int lr = lane & 15;
    const int lq8 = (lane >> 4) * 8;
    const int rq = (lane >> 4) * 4;

    f32x4 acc[4][NI] = {};

    const int srow = t >> 2;
    const int sch = (t & 3) * 8;
    char* lA = (char*)As;
    char* lB = (char*)Bs;

    for (int k0 = 0; k0 < K; k0 += 32) {
        gl_lds16(A + (size_t)(m0 + srow) * K + k0 + sch,      lA + t * 16);
        gl_lds16(A + (size_t)(m0 + 64 + srow) * K + k0 + sch, lA + 4096 + t * 16);
#pragma unroll
        for (int bseg = 0; bseg < NI / 2; ++bseg)
            gl_lds16(B + (size_t)(n0 + bseg * 64 + srow) * K + k0 + sch,
                     lB + bseg * 4096 + t * 16);
        __syncthreads();

        bf16x8 af[4], bfr[NI];
#pragma unroll
        for (int i = 0; i < 4; ++i)
            af[i] = *(const bf16x8*)&As[(wm + i * 16 + lr) * 32 + lq8];
#pragma unroll
        for (int ni = 0; ni < NI; ++ni)
            bfr[ni] = *(const bf16x8*)&Bs[(wn + ni * 16 + lr) * 32 + lq8];
#pragma unroll
        for (int mi = 0; mi < 4; ++mi)
#pragma unroll
            for (int ni = 0; ni < NI; ++ni)
                acc[mi][ni] = MFMA16(af[mi], bfr[ni], acc[mi][ni]);
        __syncthreads();
    }

#pragma unroll
    for (int mi = 0; mi < 4; ++mi) {
#pragma unroll
        for (int ni = 0; ni < NI; ++ni) {
#pragma unroll
            for (int r = 0; r < 4; ++r) {
                const int m = m0 + wm + mi * 16 + rq + r;
                const int n = n0 + wn + ni * 16 + lr;
                const float vv = acc[mi][ni][r];
                if constexpr (EP == 0) {
                    bf16* C = (bf16*)Cv;
                    const int b = m >> 11, s = m & 2047;
                    const int h = n >> 6,  d = n & 63;
                    C[(((size_t)(b * 16 + h)) * 2048 + s) * 64 + d] = (bf16)vv;
                } else if constexpr (EP == 1) {
                    float* C = (float*)Cv;
                    C[(size_t)m * 1024 + n] = vv;
                } else {
                    bf16* C = (bf16*)Cv;   // V^T: [b][h*64+d=m][s=n&2047]
                    C[((size_t)(n >> 11) * 1024 + m) * 2048 + (n & 2047)] = (bf16)vv;
                }
            }
        }
    }
}

// qkv: 128x256 tiles -> 384 blocks total = single pass at 2 blocks/CU.
__global__ __launch_bounds__(256, 2) void qkv_bf(
    const bf16* __restrict__ Xq, const bf16* __restrict__ Xk,
    const bf16* __restrict__ Xv, const bf16* __restrict__ Wc,
    bf16* __restrict__ Qb, bf16* __restrict__ Kb, bf16* __restrict__ Vb) {
    const int z = blockIdx.z;
    if (z == 0)
        gemm_bf<0, 8>(Xq, Wc, Qb, blockIdx.x * 128, blockIdx.y * 256);
    else if (z == 1)
        gemm_bf<0, 8>(Xk, Wc + 1048576, Kb, blockIdx.x * 128, blockIdx.y * 256);
    else {
        // V^T: M=1024 (weight rows), N=4096 (tokens): 8 x 16 tiles = 128 blocks
        const int id = blockIdx.y * 32 + blockIdx.x;
        gemm_bf<2, 8>(Wc + 2 * 1048576, Xv, Vb, (id & 7) * 128, (id >> 3) * 256);
    }
}

__global__ __launch_bounds__(256, 2) void out_gemm(
    const bf16* __restrict__ X, const bf16* __restrict__ W, float* __restrict__ C) {
    gemm_bf<1, 4>(X, W, C, blockIdx.x * 128, blockIdx.y * 128);
}

// ---------------------------------------------------------------------------
// Fallback qkv (fp32 tokens staged in-register) for small workspaces.
// ---------------------------------------------------------------------------
template <int MODE>
__device__ __forceinline__ void gemm_f32tok(const void* __restrict__ Av,
                                            const void* __restrict__ Bv,
                                            bf16* __restrict__ C,
                                            const int m0, const int n0) {
    constexpr int K = 1024;
    __shared__ __align__(16) bf16 As[128 * 32];
    __shared__ __align__(16) bf16 Bs[128 * 32];

    const int t = threadIdx.x;
    const int lane = t & 63;
    const int w = t >> 6;
    const int wm = (w & 1) * 64;
    const int wn = (w >> 1) * 64;
    const int lr = lane & 15;
    const int lq8 = (lane >> 4) * 8;
    const int rq = (lane >> 4) * 4;

    f32x4 acc[4][4] = {};
    const int srow = t >> 2;
    const int sch = (t & 3) * 8;
    const int ar = t >> 1;
    const int ac = (t & 1) * 16;
    char* lA = (char*)As;
    char* lB = (char*)Bs;

    for (int k0 = 0; k0 < K; k0 += 32) {
        if constexpr (MODE == 0) {
            const float* X = (const float*)Av;
            const float* p = X + (size_t)(m0 + ar) * K + k0 + ac;
            float4 f0 = ((const float4*)p)[0], f1 = ((const float4*)p)[1];
            float4 f2 = ((const float4*)p)[2], f3 = ((const float4*)p)[3];
            bf16x8 o0, o1;
            o0[0]=(bf16)f0.x; o0[1]=(bf16)f0.y; o0[2]=(bf16)f0.z; o0[3]=(bf16)f0.w;
            o0[4]=(bf16)f1.x; o0[5]=(bf16)f1.y; o0[6]=(bf16)f1.z; o0[7]=(bf16)f1.w;
            o1[0]=(bf16)f2.x; o1[1]=(bf16)f2.y; o1[2]=(bf16)f2.z; o1[3]=(bf16)f2.w;
            o1[4]=(bf16)f3.x; o1[5]=(bf16)f3.y; o1[6]=(bf16)f3.z; o1[7]=(bf16)f3.w;
            *(bf16x8*)&As[ar * 32 + ac]     = o0;
            *(bf16x8*)&As[ar * 32 + ac + 8] = o1;
        } else {
            const bf16* X = (const bf16*)Av;
            gl_lds16(X + (size_t)(m0 + srow) * K + k0 + sch,      lA + t * 16);
            gl_lds16(X + (size_t)(m0 + 64 + srow) * K + k0 + sch, lA + 4096 + t * 16);
        }
        if constexpr (MODE == 2) {
            const float* X = (const float*)Bv;
            const float* p = X + (size_t)(n0 + ar) * K + k0 + ac;
            float4 f0 = ((const float4*)p)[0], f1 = ((const float4*)p)[1];
            float4 f2 = ((const float4*)p)[2], f3 = ((const float4*)p)[3];
            bf16x8 o0, o1;
            o0[0]=(bf16)f0.x; o0[1]=(bf16)f0.y; o0[2]=(bf16)f0.z; o0[3]=(bf16)f0.w;
            o0[4]=(bf16)f1.x; o0[5]=(bf16)f1.y; o0[6]=(bf16)f1.z; o0[7]=(bf16)f1.w;
            o1[0]=(bf16)f2.x; o1[1]=(bf16)f2.y; o1[2]=(bf16)f2.z; o1[3]=(bf16)f2.w;
            o1[4]=(bf16)f3.x; o1[5]=(bf16)f3.y; o1[6]=(bf16)f3.z; o1[7]=(bf16)f3.w;
            *(bf16x8*)&Bs[ar * 32 + ac]     = o0;
            *(bf16x8*)&Bs[ar * 32 + ac + 8] = o1;
        } else {
            const bf16* W = (const bf16*)Bv;
            gl_lds16(W + (size_t)(n0 + srow) * K + k0 + sch,      lB + t * 16);
            gl_lds16(W + (size_t)(n0 + 64 + srow) * K + k0 + sch, lB + 4096 + t * 16);
        }
        __syncthreads();

        bf16x8 af[4], bfr[4];
#pragma unroll
        for (int i = 0; i < 4; ++i) {
            af[i]  = *(const bf16x8*)&As[(wm + i * 16 + lr) * 32 + lq8];
            bfr[i] = *(const bf16x8*)&Bs[(wn + i * 16 + lr) * 32 + lq8];
        }
#pragma unroll
        for (int mi = 0; mi < 4; ++mi)
#pragma unroll
            for (int ni = 0; ni < 4; ++ni)
                acc[mi][ni] = MFMA16(af[mi], bfr[ni], acc[mi][ni]);
        __syncthreads();
    }

#pragma unroll
    for (int mi = 0; mi < 4; ++mi) {
#pragma unroll
        for (int ni = 0; ni < 4; ++ni) {
#pragma unroll
            for (int r = 0; r < 4; ++r) {
                const int m = m0 + wm + mi * 16 + rq + r;
                const int n = n0 + wn + ni * 16 + lr;
                const float vv = acc[mi][ni][r];
                if constexpr (MODE == 0) {
                    const int b = m >> 11, s = m & 2047;
                    const int h = n >> 6,  d = n & 63;
                    C[(((size_t)(b * 16 + h)) * 2048 + s) * 64 + d] = (bf16)vv;
                } else {
                    C[((size_t)(n >> 11) * 1024 + m) * 2048 + (n & 2047)] = (bf16)vv;
                }
            }
        }
    }
}

__global__ __launch_bounds__(256, 2) void qkv_f32(
    const float* __restrict__ q, const float* __restrict__ k, const float* __restrict__ v,
    const bf16* __restrict__ Wc, bf16* __restrict__ Qb, bf16* __restrict__ Kb,
    bf16* __restrict__ Vb) {
    const int z = blockIdx.z;
    if (z == 0)
        gemm_f32tok<0>(q, Wc, Qb, blockIdx.x * 128, blockIdx.y * 128);
    else if (z == 1)
        gemm_f32tok<0>(k, Wc + 1048576, Kb, blockIdx.x * 128, blockIdx.y * 128);
    else
        gemm_f32tok<2>(Wc + 2 * 1048576, v, Vb, blockIdx.y * 128, blockIdx.x * 128);
}

// ---------------------------------------------------------------------------
// Fused flash attention v4: Q-tile 128 (32 q-rows/wave), K-tile 64.
// LDS traffic per unit work cut ~40% vs v3: B-fragments (bk/bv) and K/V
// staging amortize over 2 A-fragments per wave. Xor-swizzled (0 conflicts,
// verified R6), wave-private P (2 barriers/iter), fixed-max softmax in log2
// domain, row-sum l rides as V^T ones row (5th PV accumulator).
// LDS 50 KB -> 2 blocks/CU; grid 512 = one pass.
// ---------------------------------------------------------------------------
__global__ __launch_bounds__(256, 2) void attn_kernel(
    const bf16* __restrict__ Qb, const bf16* __restrict__ Kb,
    const bf16* __restrict__ Vb, bf16* __restrict__ Xb) {
    constexpr int S = 2048;

    __shared__ __align__(16) bf16 Qs[128 * 64];  // 16 KB
    __shared__ __align__(16) bf16 Ks[64 * 64];   // 8 KB
    __shared__ __align__(16) bf16 Ps[128 * 64];  // 16 KB (wave-private rows)
    __shared__ __align__(16) bf16 Vt[80 * 64];   // 10 KB (rows 64..79: ones)

    const int t = threadIdx.x;
    const int lane = t & 63;
    const int w = t >> 6;
    const int lr = lane & 15;
    const int lq8 = (lane >> 4) * 8;
    const int q4 = (lane >> 4) * 4;
    const int bh = blockIdx.y;
    const int q0 = blockIdx.x * 128;
    const bf16* Q  = Qb + (size_t)bh * S * 64;   // [s][d]
    const bf16* Kh = Kb + (size_t)bh * S * 64;   // [s][d]
    const bf16* Vh = Vb + (size_t)bh * 64 * S;   // [d][s]

    // Q stage (scaled into log2 domain), swizzled chunk ^ (row&7)
    const float qscale = 0.125f * 1.4426950408889634f;
#pragma unroll
    for (int p = 0; p < 4; ++p) {
        const int c = p * 256 + t;
        const int row = c >> 3, cc = c & 7;
        bf16x8 vq = *(const bf16x8*)(Q + (size_t)(q0 + row) * 64 + cc * 8);
#pragma unroll
        for (int e = 0; e < 8; ++e) vq[e] = (bf16)((float)vq[e] * qscale);
        *(bf16x8*)&Qs[row * 64 + (cc ^ (row & 7)) * 8] = vq;
    }
    // ones tile (row 64 = 1, 65..79 = 0; constant rows are swizzle-invariant)
    for (int idx = t; idx < 1024; idx += 256) {
        const int r = idx >> 6;
        Vt[(64 + r) * 64 + (idx & 63)] = (r == 0) ? (bf16)1.0f : (bf16)0.0f;
    }

    f32x4 oacc[2][5] = {};

    // staging: 4 threads/row, 2 chunks each (64 rows x 8 chunks)
    const int srow = t >> 2;
    const int scc = (t & 3) * 2;
    bf16x8 pk[2], pv[2];
#pragma unroll
    for (int c = 0; c < 2; ++c) {
        pk[c] = *(const bf16x8*)(Kh + (size_t)srow * 64 + (scc + c) * 8);
        pv[c] = *(const bf16x8*)(Vh + (size_t)srow * S + (scc + c) * 8);
    }

    const int swzA = (lr & 7) << 3;              // Q/K/V swizzle (rows = lr mod 8)
    const int swzP = ((lr >> 1) & 7) << 3;       // P swizzle

    for (int j = 0; j < S / 64; ++j) {
        __syncthreads();  // (A) prev K/V reads done
#pragma unroll
        for (int c = 0; c < 2; ++c) {
            *(bf16x8*)&Ks[srow * 64 + ((scc + c) ^ (srow & 7)) * 8] = pk[c];
            *(bf16x8*)&Vt[srow * 64 + ((scc + c) ^ (srow & 7)) * 8] = pv[c];
        }
        __syncthreads();  // (B) staging visible

        // scores: wave rows w*32..+31 x 64 keys
        f32x4 sacc[2][4] = {};
#pragma unroll
        for (int ks = 0; ks < 64; ks += 32) {
            bf16x8 af[2], bk[4];
#pragma unroll
            for (int mt = 0; mt < 2; ++mt)
                af[mt] = *(const bf16x8*)&Qs[(w * 32 + mt * 16 + lr) * 64 + ((ks + lq8) ^ swzA)];
#pragma unroll
            for (int nt = 0; nt < 4; ++nt)
                bk[nt] = *(const bf16x8*)&Ks[(nt * 16 + lr) * 64 + ((ks + lq8) ^ swzA)];
#pragma unroll
            for (int mt = 0; mt < 2; ++mt)
#pragma unroll
                for (int nt = 0; nt < 4; ++nt)
                    sacc[mt][nt] = MFMA16(af[mt], bk[nt], sacc[mt][nt]);
        }

        // prefetch next K/V tile (hidden behind exp + PV)
        if (j + 1 < S / 64) {
            const bf16* Kt = Kh + (size_t)(j + 1) * 64 * 64;
            const bf16* Vg = Vh + (size_t)(j + 1) * 64;
#pragma unroll
            for (int c = 0; c < 2; ++c) {
                pk[c] = *(const bf16x8*)(Kt + (size_t)srow * 64 + (scc + c) * 8);
                pv[c] = *(const bf16x8*)(Vg + (size_t)srow * S + (scc + c) * 8);
            }
        }

        // P = exp2(s) (guarded), write to wave-private Ps
#pragma unroll
        for (int mt = 0; mt < 2; ++mt) {
#pragma unroll
            for (int r = 0; r < 4; ++r) {
                const int row = w * 32 + mt * 16 + q4 + r;
                const int swz = ((row >> 1) & 7) << 3;
#pragma unroll
                for (int nt = 0; nt < 4; ++nt)
                    Ps[row * 64 + ((nt * 16 + lr) ^ swz)] =
                        (bf16)exp2f(fminf(sacc[mt][nt][r], 100.f));
            }
        }

        // O += P @ [V | ones]  (wave-local LDS ordering; no barrier)
#pragma unroll
        for (int ks = 0; ks < 64; ks += 32) {
            bf16x8 ap[2], bv[5];
#pragma unroll
            for (int mt = 0; mt < 2; ++mt)
                ap[mt] = *(const bf16x8*)&Ps[(w * 32 + mt * 16 + lr) * 64 + ((ks + lq8) ^ swzP)];
#pragma unroll
            for (int nt2 = 0; nt2 < 5; ++nt2)
                bv[nt2] = *(const bf16x8*)&Vt[(nt2 * 16 + lr) * 64 + ((ks + lq8) ^ swzA)];
#pragma unroll
            for (int mt = 0; mt < 2; ++mt)
#pragma unroll
                for (int nt2 = 0; nt2 < 5; ++nt2)
                    oacc[mt][nt2] = MFMA16(ap[mt], bv[nt2], oacc[mt][nt2]);
        }
    }

    // epilogue: l sits in oacc[mt][4][r] at lr==0 lanes of each quad group
    const int b = bh >> 4, h = bh & 15;
#pragma unroll
    for (int mt = 0; mt < 2; ++mt) {
#pragma unroll
        for (int r = 0; r < 4; ++r) {
            const float lv = __shfl(oacc[mt][4][r], lane & 48, 64);
            const float inv = 1.f / fmaxf(lv, 1e-30f);
            const int row = w * 32 + mt * 16 + q4 + r;
            const size_t base = ((size_t)(b * 2048 + q0 + row)) * 1024 + h * 64;
#pragma unroll
            for (int nt2 = 0; nt2 < 4; ++nt2)
                Xb[base + nt2 * 16 + lr] = (bf16)(oacc[mt][nt2][r] * inv);
        }
    }
}

extern "C" void kernel_launch(void* const* d_in, const int* in_sizes, int n_in,
                              void* d_out, int out_size, void* d_ws, size_t ws_size,
                              hipStream_t stream) {
    const float* q  = (const float*)d_in[0];
    const float* k  = (const float*)d_in[1];
    const float* v  = (const float*)d_in[2];
    const float* wq = (const float*)d_in[4];
    const float* wk = (const float*)d_in[5];
    const float* wv = (const float*)d_in[6];
    const float* wo = (const float*)d_in[7];
    float* out = (float*)d_out;

    const bool big = ws_size >= (size_t)64 * 1024 * 1024;
    bf16* Wc = (bf16*)d_ws;
    const dim3 blk(256);

    if (big) {
        bf16* Xq = Wc + 4 * 1048576;
        bf16* Xk = Xq + 4194304;
        bf16* Xv = Xk + 4194304;
        bf16* Qb = Xv + 4194304;
        bf16* Kb = Qb + 4194304;
        bf16* Vb = Kb + 4194304;          // [2,16,64,2048] (V^T)
        bf16* Xb = Vb + 4194304;
        cvt7<<<dim3(2048, 7), blk, 0, stream>>>(wq, wk, wv, wo, q, k, v, Wc);
        qkv_bf<<<dim3(32, 4, 3), blk, 0, stream>>>(Xq, Xk, Xv, Wc, Qb, Kb, Vb);
        attn_kernel<<<dim3(16, 32), blk, 0, stream>>>(Qb, Kb, Vb, Xb);
        out_gemm<<<dim3(32, 8), blk, 0, stream>>>(Xb, Wc + 3 * 1048576, out);
    } else {
        bf16* Qb = Wc + 4 * 1048576;
        bf16* Kb = Qb + 4194304;
        bf16* Vb = Kb + 4194304;
        bf16* Xb = Vb + 4194304;
        cvt7<<<dim3(512, 4), blk, 0, stream>>>(wq, wk, wv, wo, q, k, v, Wc);
        qkv_f32<<<dim3(32, 8, 3), blk, 0, stream>>>(q, k, v, Wc, Qb, Kb, Vb);
        attn_kernel<<<dim3(16, 32), blk, 0, stream>>>(Qb, Kb, Vb, Xb);
        out_gemm<<<dim3(32, 8), blk, 0, stream>>>(Xb, Wc + 3 * 1048576, out);
    }
}